// Round 6
// baseline (787.103 us; speedup 1.0000x reference)
//
#include <hip/hip_runtime.h>
#include <hip/hip_bf16.h>

typedef __bf16 bf16_t;
typedef __bf16 bf16x8 __attribute__((ext_vector_type(8)));
typedef float  f32x4  __attribute__((ext_vector_type(4)));

#define GAS __attribute__((address_space(1)))
#define LAS __attribute__((address_space(3)))

__device__ __forceinline__ void gload_lds16(const bf16_t* g, bf16_t* l) {
    __builtin_amdgcn_global_load_lds((const GAS void*)g, (LAS void*)l, 16, 0, 0);
}

#define QSCALE 0.044194173824159216f  /* 1/sqrt(512) */
#define L2E    1.4426950408889634f

// ---------------- split fp32 -> (hi, lo) bf16 ----------------
__global__ __launch_bounds__(256) void k_split_x(const float* __restrict__ X,
                                                 bf16_t* __restrict__ H,
                                                 bf16_t* __restrict__ L, int n) {
    int i = (blockIdx.x * 256 + threadIdx.x) * 4;
    if (i >= n) return;
    float4 v = *(const float4*)(X + i);
    float vv[4] = {v.x, v.y, v.z, v.w};
    union { bf16_t b[4]; uint2 u; } hh, ll;
#pragma unroll
    for (int j = 0; j < 4; j++) {
        bf16_t h = (bf16_t)vv[j];
        hh.b[j] = h;
        ll.b[j] = (bf16_t)(vv[j] - (float)h);
    }
    *(uint2*)(H + i) = hh.u;
    *(uint2*)(L + i) = ll.u;
}

// ---------------- W[3,512,512] -> WT[3,512(o),512(d)] split ----------------
__global__ __launch_bounds__(256) void k_split_wt(const float* __restrict__ W,
                                                  bf16_t* __restrict__ H,
                                                  bf16_t* __restrict__ L) {
    int t = blockIdx.x * 256 + threadIdx.x;
    int base = t * 4;
    int m = base >> 18;
    int o = (base >> 9) & 511;
    int d = base & 511;
    union { bf16_t b[4]; uint2 u; } hh, ll;
#pragma unroll
    for (int j = 0; j < 4; j++) {
        float w = W[m * 262144 + (d + j) * 512 + o];
        bf16_t h = (bf16_t)w;
        hh.b[j] = h;
        ll.b[j] = (bf16_t)(w - (float)h);
    }
    *(uint2*)(H + base) = hh.u;
    *(uint2*)(L + base) = ll.u;
}

// -------- QKV projection GEMM-NT, 128x128 tile, BK=32, split bf16x3 --------
__global__ __launch_bounds__(256) void k_qkv(
    const bf16_t* __restrict__ Ah, const bf16_t* __restrict__ Al,
    const bf16_t* __restrict__ Bh, const bf16_t* __restrict__ Bl,
    bf16_t* __restrict__ Qh, bf16_t* __restrict__ Ql,
    bf16_t* __restrict__ Kh, bf16_t* __restrict__ Kl,
    bf16_t* __restrict__ VT) {
    __shared__ bf16_t lds[16384];
    bf16_t* As_h = lds;
    bf16_t* Bs_h = lds + 4096;
    bf16_t* As_l = lds + 8192;
    bf16_t* Bs_l = lds + 12288;

    const int tid = threadIdx.x;
    const int lane = tid & 63;
    const int wid = tid >> 6;
    const int wr = wid >> 1, wc = wid & 1;
    const size_t i0 = (size_t)blockIdx.y * 128;
    const size_t j0 = (size_t)blockIdx.x * 128;

    const bf16_t* pAh = Ah + i0 * 512;
    const bf16_t* pBh = Bh + j0 * 512;
    const bf16_t* pAl = Al + i0 * 512;
    const bf16_t* pBl = Bl + j0 * 512;

    const int srow = tid >> 2;
    const int scoff = (tid & 3) * 8;

    f32x4 acc[4][4] = {};

    const int arow = wr * 64 + (lane & 15);
    const int brow = wc * 64 + (lane & 15);
    const int ko = (lane >> 4) * 8;

    for (int kt = 0; kt < 512; kt += 32) {
#pragma unroll
        for (int c = 0; c < 2; c++) {
            const size_t ra = (size_t)(c * 64 + srow) * 512 + kt + scoff;
            const int loff = c * 2048 + tid * 8;
            gload_lds16(pAh + ra, As_h + loff);
            gload_lds16(pBh + ra, Bs_h + loff);
            gload_lds16(pAl + ra, As_l + loff);
            gload_lds16(pBl + ra, Bs_l + loff);
        }
        __syncthreads();

        bf16x8 ah[4], bh[4], al[4], bl[4];
#pragma unroll
        for (int m = 0; m < 4; m++) ah[m] = *(const bf16x8*)&As_h[(arow + m * 16) * 32 + ko];
#pragma unroll
        for (int n = 0; n < 4; n++) bh[n] = *(const bf16x8*)&Bs_h[(brow + n * 16) * 32 + ko];
#pragma unroll
        for (int m = 0; m < 4; m++) al[m] = *(const bf16x8*)&As_l[(arow + m * 16) * 32 + ko];
#pragma unroll
        for (int n = 0; n < 4; n++) bl[n] = *(const bf16x8*)&Bs_l[(brow + n * 16) * 32 + ko];
        __builtin_amdgcn_s_setprio(1);
#pragma unroll
        for (int m = 0; m < 4; m++)
#pragma unroll
            for (int n = 0; n < 4; n++) {
                acc[m][n] = __builtin_amdgcn_mfma_f32_16x16x32_bf16(ah[m], bh[n], acc[m][n], 0, 0, 0);
                acc[m][n] = __builtin_amdgcn_mfma_f32_16x16x32_bf16(ah[m], bl[n], acc[m][n], 0, 0, 0);
                acc[m][n] = __builtin_amdgcn_mfma_f32_16x16x32_bf16(al[m], bh[n], acc[m][n], 0, 0, 0);
            }
        __builtin_amdgcn_s_setprio(0);
        __syncthreads();
    }

#pragma unroll
    for (int m = 0; m < 4; m++) {
#pragma unroll
        for (int n = 0; n < 4; n++) {
#pragma unroll
            for (int j = 0; j < 4; j++) {
                const size_t gr = i0 + wr * 64 + m * 16 + (lane >> 4) * 4 + j;
                const size_t gc = j0 + wc * 64 + n * 16 + (lane & 15);
                float v = acc[m][n][j];
                const int mat = (int)(gc >> 9);
                const size_t bloc = gr >> 11;
                const size_t nrow = gr & 2047;
                const size_t o = gc & 511;
                const size_t idx = bloc * 1048576 + nrow * 512 + o;
                if (mat == 0) {
                    float v2 = v * QSCALE;
                    bf16_t h = (bf16_t)v2;
                    Qh[idx] = h; Ql[idx] = (bf16_t)(v2 - (float)h);
                } else if (mat == 1) {
                    bf16_t h = (bf16_t)v;
                    Kh[idx] = h; Kl[idx] = (bf16_t)(v - (float)h);
                } else {
                    VT[bloc * 1048576 + o * 2048 + nrow] = (bf16_t)v;
                }
            }
        }
    }
}

// ---------------- fused flash attention, KVBLK=128 ----------------
// Grid (32, G), 512 thr / 8 waves. QBLK=64 q-rows, 16 kv-tiles of 128.
// Wave (mg,kg) = (wid>>2, wid&3): QK 32q x 32kv; PV same rows, o-quarter kg.
// LDS: chunk dbuf 2x48KB [Qh|Ql|Kh|Kl] + P 16KB + MP/SP 2KB. V: direct
// global->reg (each V frag owned by one wave; L2-resident after T1 swizzle).
#define CH_SZ   49152
#define PT_OFF  98304
#define MP_OFF  114688
#define SP_OFF  115712

__global__ __launch_bounds__(512) void k_flash(
    const bf16_t* __restrict__ Qh, const bf16_t* __restrict__ Ql,
    const bf16_t* __restrict__ Kh, const bf16_t* __restrict__ Kl,
    const bf16_t* __restrict__ VT, float* __restrict__ Out) {
    __shared__ __align__(16) char smem[116736];

    const int tid = threadIdx.x;
    const int l = tid & 63, wid = tid >> 6;
    const int l15 = l & 15, l4 = l >> 4;
    const int mg = wid >> 2, kg = wid & 3;
    const int gsw = l15 & 7;

    // ---- XCD swizzle (bijective: total divisible by 8) ----
    const int total = gridDim.x * gridDim.y;
    const int f = blockIdx.x + gridDim.x * blockIdx.y;
    const int fp = (f & 7) * (total >> 3) + (f >> 3);
    const int b = fp >> 5;
    const int q0 = (fp & 31) * 64;
    const size_t NB = 1048576;

    const bf16_t* qhb = Qh + (size_t)b * NB;
    const bf16_t* qlb = Ql + (size_t)b * NB;
    const bf16_t* khb = Kh + (size_t)b * NB;
    const bf16_t* klb = Kl + (size_t)b * NB;
    const bf16_t* vtb = VT + (size_t)b * NB;

    float* MP = (float*)(smem + MP_OFF);   // [4][64] tile-max partials
    float* SP = (float*)(smem + SP_OFF);   // [4][64] exp-sum partials

    f32x4 O[2][8] = {};
    float mreg[2][4], lreg[2][4];
#pragma unroll
    for (int mf = 0; mf < 2; mf++)
#pragma unroll
        for (int j = 0; j < 4; j++) { mreg[mf][j] = -3e38f; lreg[mf][j] = 0.f; }

    const int srow8 = tid >> 3;
    const int sgl = (tid & 7) ^ (srow8 & 7);

    // stage one 64-k chunk (Q 64 rows hi/lo + K 128 rows hi/lo) for tile t
    auto stage_chunk = [&](int t, int kc, int b2) {
        const int co = kc * 64 + sgl * 8;
        bf16_t* d = (bf16_t*)(smem + b2 * CH_SZ) + tid * 8;
        gload_lds16(qhb + (size_t)(q0 + srow8) * 512 + co, d);
        gload_lds16(qlb + (size_t)(q0 + srow8) * 512 + co, d + 4096);
        gload_lds16(khb + (size_t)(t * 128 + srow8) * 512 + co, d + 8192);
        gload_lds16(khb + (size_t)(t * 128 + 64 + srow8) * 512 + co, d + 12288);
        gload_lds16(klb + (size_t)(t * 128 + srow8) * 512 + co, d + 16384);
        gload_lds16(klb + (size_t)(t * 128 + 64 + srow8) * 512 + co, d + 20480);
    };

    stage_chunk(0, 0, 0);
    stage_chunk(0, 1, 1);

    const int rb0 = mg * 32 + l4 * 4;      // softmax/O row base (+ mf*16)
    const int arowb = mg * 32 + l15;       // A-frag row base (+ mf*16)

#pragma unroll 1
    for (int t = 0; t < 16; ++t) {
        f32x4 S[2][2] = {};
#pragma unroll
        for (int kc = 0; kc < 8; ++kc) {
            if (kc == 0) asm volatile("s_waitcnt vmcnt(6)" ::: "memory");
            else         asm volatile("s_waitcnt vmcnt(0)" ::: "memory");
            __builtin_amdgcn_s_barrier();
            if (kc >= 1 && kc <= 6)      stage_chunk(t, kc + 1, (kc + 1) & 1);
            else if (kc == 7 && t < 15)  stage_chunk(t + 1, 0, 0);

            const char* CB = smem + (kc & 1) * CH_SZ;
#pragma unroll
            for (int ks = 0; ks < 2; ++ks) {
                const int gph = ((ks * 4 + l4) ^ gsw) << 4;
                bf16x8 ah[2], al[2], bh[2], bl[2];
#pragma unroll
                for (int mf = 0; mf < 2; mf++) {
                    ah[mf] = *(const bf16x8*)(CB + (arowb + mf * 16) * 128 + gph);
                    al[mf] = *(const bf16x8*)(CB + 8192 + (arowb + mf * 16) * 128 + gph);
                }
#pragma unroll
                for (int nf = 0; nf < 2; nf++) {
                    const int brow = kg * 32 + nf * 16 + l15;
                    bh[nf] = *(const bf16x8*)(CB + 16384 + brow * 128 + gph);
                    bl[nf] = *(const bf16x8*)(CB + 32768 + brow * 128 + gph);
                }
                __builtin_amdgcn_s_setprio(1);
#pragma unroll
                for (int mf = 0; mf < 2; mf++)
#pragma unroll
                    for (int nf = 0; nf < 2; nf++) {
                        S[mf][nf] = __builtin_amdgcn_mfma_f32_16x16x32_bf16(ah[mf], bh[nf], S[mf][nf], 0, 0, 0);
                        S[mf][nf] = __builtin_amdgcn_mfma_f32_16x16x32_bf16(ah[mf], bl[nf], S[mf][nf], 0, 0, 0);
                        S[mf][nf] = __builtin_amdgcn_mfma_f32_16x16x32_bf16(al[mf], bh[nf], S[mf][nf], 0, 0, 0);
                    }
                __builtin_amdgcn_s_setprio(0);
            }
        }

        // ---- online softmax ----
        float pm[2][4];
#pragma unroll
        for (int mf = 0; mf < 2; mf++)
#pragma unroll
            for (int j = 0; j < 4; j++) pm[mf][j] = fmaxf(S[mf][0][j], S[mf][1][j]);
#pragma unroll
        for (int off = 1; off < 16; off <<= 1)
#pragma unroll
            for (int mf = 0; mf < 2; mf++)
#pragma unroll
                for (int j = 0; j < 4; j++) pm[mf][j] = fmaxf(pm[mf][j], __shfl_xor(pm[mf][j], off));
        if (l15 == 0) {
#pragma unroll
            for (int mf = 0; mf < 2; mf++) {
                f32x4 v; v[0] = pm[mf][0]; v[1] = pm[mf][1]; v[2] = pm[mf][2]; v[3] = pm[mf][3];
                *(f32x4*)(MP + kg * 64 + rb0 + mf * 16) = v;
            }
        }
        asm volatile("s_waitcnt lgkmcnt(0)" ::: "memory");
        __builtin_amdgcn_s_barrier();
        if (t < 15) stage_chunk(t + 1, 1, 1);

        float mnew[2][4];
#pragma unroll
        for (int mf = 0; mf < 2; mf++) {
            f32x4 g0 = *(const f32x4*)(MP + 0 * 64 + rb0 + mf * 16);
            f32x4 g1 = *(const f32x4*)(MP + 1 * 64 + rb0 + mf * 16);
            f32x4 g2 = *(const f32x4*)(MP + 2 * 64 + rb0 + mf * 16);
            f32x4 g3 = *(const f32x4*)(MP + 3 * 64 + rb0 + mf * 16);
#pragma unroll
            for (int j = 0; j < 4; j++)
                mnew[mf][j] = fmaxf(mreg[mf][j],
                                    fmaxf(fmaxf(g0[j], g1[j]), fmaxf(g2[j], g3[j])));
        }
        float p[2][2][4], ps[2][4];
#pragma unroll
        for (int mf = 0; mf < 2; mf++)
#pragma unroll
            for (int nf = 0; nf < 2; nf++)
#pragma unroll
                for (int j = 0; j < 4; j++)
                    p[mf][nf][j] = exp2f((S[mf][nf][j] - mnew[mf][j]) * L2E);
#pragma unroll
        for (int mf = 0; mf < 2; mf++)
#pragma unroll
            for (int j = 0; j < 4; j++) ps[mf][j] = p[mf][0][j] + p[mf][1][j];
#pragma unroll
        for (int off = 1; off < 16; off <<= 1)
#pragma unroll
            for (int mf = 0; mf < 2; mf++)
#pragma unroll
                for (int j = 0; j < 4; j++) ps[mf][j] += __shfl_xor(ps[mf][j], off);
        if (l15 == 0) {
#pragma unroll
            for (int mf = 0; mf < 2; mf++) {
                f32x4 v; v[0] = ps[mf][0]; v[1] = ps[mf][1]; v[2] = ps[mf][2]; v[3] = ps[mf][3];
                *(f32x4*)(SP + kg * 64 + rb0 + mf * 16) = v;
            }
        }
        // P -> bf16 swizzled LDS tile [64][128]
#pragma unroll
        for (int mf = 0; mf < 2; mf++)
#pragma unroll
            for (int nf = 0; nf < 2; nf++)
#pragma unroll
                for (int j = 0; j < 4; j++) {
                    const int row = rb0 + mf * 16 + j;
                    const int phys = (kg * 4 + nf * 2 + (l15 >> 3)) ^ (row & 7);
                    *(bf16_t*)(smem + PT_OFF + row * 256 + phys * 16 + (l15 & 7) * 2) =
                        (bf16_t)p[mf][nf][j];
                }
        asm volatile("s_waitcnt lgkmcnt(0)" ::: "memory");
        __builtin_amdgcn_s_barrier();

        // ---- PV: rescale O, accumulate P*V (V direct from global) ----
#pragma unroll
        for (int mf = 0; mf < 2; mf++) {
            f32x4 s0 = *(const f32x4*)(SP + 0 * 64 + rb0 + mf * 16);
            f32x4 s1 = *(const f32x4*)(SP + 1 * 64 + rb0 + mf * 16);
            f32x4 s2 = *(const f32x4*)(SP + 2 * 64 + rb0 + mf * 16);
            f32x4 s3 = *(const f32x4*)(SP + 3 * 64 + rb0 + mf * 16);
            float fr[4];
#pragma unroll
            for (int j = 0; j < 4; j++) {
                fr[j] = exp2f((mreg[mf][j] - mnew[mf][j]) * L2E);
                lreg[mf][j] = lreg[mf][j] * fr[j] + s0[j] + s1[j] + s2[j] + s3[j];
                mreg[mf][j] = mnew[mf][j];
            }
#pragma unroll
            for (int nf = 0; nf < 8; nf++)
#pragma unroll
                for (int j = 0; j < 4; j++) O[mf][nf][j] *= fr[j];
        }
#pragma unroll
        for (int ks = 0; ks < 4; ++ks) {
            const int gph = ((ks * 4 + l4) ^ gsw) << 4;
            bf16x8 vb[8], pa[2];
#pragma unroll
            for (int nf = 0; nf < 8; nf++)
                vb[nf] = *(const bf16x8*)(vtb + (size_t)(kg * 128 + nf * 16 + l15) * 2048 +
                                          t * 128 + ks * 32 + l4 * 8);
#pragma unroll
            for (int mf = 0; mf < 2; mf++)
                pa[mf] = *(const bf16x8*)(smem + PT_OFF + (mg * 32 + mf * 16 + l15) * 256 + gph);
            __builtin_amdgcn_s_setprio(1);
#pragma unroll
            for (int nf = 0; nf < 8; nf++)
#pragma unroll
                for (int mf = 0; mf < 2; mf++)
                    O[mf][nf] = __builtin_amdgcn_mfma_f32_16x16x32_bf16(pa[mf], vb[nf], O[mf][nf], 0, 0, 0);
            __builtin_amdgcn_s_setprio(0);
        }
    }

    // ---- epilogue: O / l ----
#pragma unroll
    for (int mf = 0; mf < 2; mf++) {
        float inv[4];
#pragma unroll
        for (int j = 0; j < 4; j++) inv[j] = 1.0f / lreg[mf][j];
#pragma unroll
        for (int nf = 0; nf < 8; nf++)
#pragma unroll
            for (int j = 0; j < 4; j++) {
                const size_t row = q0 + mg * 32 + mf * 16 + l4 * 4 + j;
                const size_t col = kg * 128 + nf * 16 + l15;
                Out[(size_t)b * NB + row * 512 + col] = O[mf][nf][j] * inv[j];
            }
    }
}

extern "C" void kernel_launch(void* const* d_in, const int* in_sizes, int n_in,
                              void* d_out, int out_size, void* d_ws, size_t ws_size,
                              hipStream_t stream) {
    const float* x = (const float*)d_in[0];
    const float* w = (const float*)d_in[1];
    float* out = (float*)d_out;

    const size_t NB = (size_t)2048 * 512;
    const size_t NW = (size_t)3 * 512 * 512;

    const size_t perG = 7 * NB * 2;
    size_t fixed = 2 * NW * 2 + 4096;
    int G = 1;
    if (ws_size > fixed + perG) {
        size_t g = (ws_size - fixed) / perG;
        G = (int)(g > 16 ? 16 : g);
    } else {
        return;  // workspace too small (needs ~17 MB)
    }

    size_t off = 0;
    char* wsb = (char*)d_ws;
    auto take = [&](size_t bytes) -> char* {
        char* p = wsb + off;
        off = (off + bytes + 255) & ~(size_t)255;
        return p;
    };
    bf16_t* wth = (bf16_t*)take(NW * 2);
    bf16_t* wtl = (bf16_t*)take(NW * 2);
    bf16_t* xh = (bf16_t*)take(G * NB * 2);
    bf16_t* xl = (bf16_t*)take(G * NB * 2);
    bf16_t* qh = (bf16_t*)take(G * NB * 2);
    bf16_t* ql = (bf16_t*)take(G * NB * 2);
    bf16_t* kh = (bf16_t*)take(G * NB * 2);
    bf16_t* kl = (bf16_t*)take(G * NB * 2);
    bf16_t* vt = (bf16_t*)take(G * NB * 2);

    k_split_wt<<<dim3((unsigned)(NW / 4 / 256)), 256, 0, stream>>>(w, wth, wtl);

    for (int g0 = 0; g0 < 16; g0 += G) {
        const int Gc = (16 - g0 < G) ? (16 - g0) : G;
        const size_t base = (size_t)g0 * NB;
        k_split_x<<<dim3((unsigned)(Gc * NB / 4 / 256)), 256, 0, stream>>>(
            x + base, xh, xl, (int)(Gc * NB));
        k_qkv<<<dim3(12, 16 * Gc), 256, 0, stream>>>(
            xh, xl, wth, wtl, qh, ql, kh, kl, vt);
        k_flash<<<dim3(32, Gc), 512, 0, stream>>>(
            qh, ql, kh, kl, vt, out + base);
    }
}